// Round 14
// baseline (147.006 us; speedup 1.0000x reference)
//
#include <hip/hip_runtime.h>

typedef __attribute__((ext_vector_type(8))) __bf16 bf16x8;
typedef __attribute__((ext_vector_type(4))) float f32x4;
typedef __attribute__((ext_vector_type(8))) unsigned short u16x8;
typedef __attribute__((ext_vector_type(4))) unsigned short u16x4;

#define MFMA16(a, b, c) __builtin_amdgcn_mfma_f32_16x16x32_bf16((a), (b), (c), 0, 0, 0)

static __device__ __forceinline__ unsigned short f2bf(float f) {
    union { float f; unsigned int u; } v;
    v.f = f;
    unsigned int r = v.u + 0x7FFFu + ((v.u >> 16) & 1u);
    return (unsigned short)(r >> 16);
}
static __device__ __forceinline__ float bf2f(unsigned short u) {
    union { unsigned int u; float f; } v;
    v.u = ((unsigned int)u) << 16;
    return v.f;
}

// ------------------------------------------------------------------
// prep: weights -> bf16 MFMA B-fragment order (wfrag for Q, kv_wf for K/V).
// ------------------------------------------------------------------
__global__ __launch_bounds__(256) void prep_kernel(
    const float* __restrict__ qw, const float* __restrict__ kw,
    const float* __restrict__ vw,
    unsigned short* __restrict__ wfrag, unsigned short* __restrict__ kv_wf)
{
    const int idx = blockIdx.x * 256 + threadIdx.x;
    if (idx < 262144) {
        const int i = idx & 7, lane = (idx >> 3) & 63, kk = (idx >> 9) & 15, nb = idx >> 13;
        const int row = nb * 16 + (lane & 15);
        const int col = kk * 32 + ((lane >> 4) << 3) + i;
        wfrag[idx] = f2bf(qw[row * 512 + col]);
    } else {
        const int jdx = idx - 262144;
        const int i = jdx & 7, lane = (jdx >> 3) & 63;
        const int rest = jdx >> 9;
        const int kk = rest % 24, nb = rest / 24;
        const int j = nb * 16 + (lane & 15);
        const int k = kk * 32 + ((lane >> 4) << 3) + i;
        kv_wf[jdx] = f2bf(j < 512 ? kw[j * 768 + k] : vw[(j - 512) * 768 + k]);
    }
}

// ------------------------------------------------------------------
// kv: fused LN(xf) + K/V projection. grid (jt=16, b=16). block = 256.
// ------------------------------------------------------------------
#define LDK 776
__global__ __launch_bounds__(256) void kv_kernel(
    const float* __restrict__ xf, const unsigned short* __restrict__ kv_wf,
    const float* __restrict__ kb, const float* __restrict__ vb,
    const float* __restrict__ tg, const float* __restrict__ tb,
    float* __restrict__ kv)
{
    __shared__ unsigned short xfn[80 * LDK];
    const int tid = threadIdx.x;
    const int lane = tid & 63;
    const int w = tid >> 6;
    const int l15 = lane & 15;
    const int lg = lane >> 4;
    const int b = blockIdx.y;
    const int jt = blockIdx.x;

    float g[12], be[12];
#pragma unroll
    for (int c = 0; c < 3; ++c) {
        const float4 gv = *(const float4*)(tg + c * 256 + lane * 4);
        const float4 bv = *(const float4*)(tb + c * 256 + lane * 4);
        g[c*4+0]=gv.x; g[c*4+1]=gv.y; g[c*4+2]=gv.z; g[c*4+3]=gv.w;
        be[c*4+0]=bv.x; be[c*4+1]=bv.y; be[c*4+2]=bv.z; be[c*4+3]=bv.w;
    }

    for (int n = w; n < 77; n += 4) {
        const float* xr = xf + (long)(b * 77 + n) * 768;
        float vals[12];
#pragma unroll
        for (int c = 0; c < 3; ++c) {
            const float4 v4 = *(const float4*)(xr + c * 256 + lane * 4);
            vals[c*4+0]=v4.x; vals[c*4+1]=v4.y; vals[c*4+2]=v4.z; vals[c*4+3]=v4.w;
        }
        float s = 0.f, ss = 0.f;
#pragma unroll
        for (int j = 0; j < 12; ++j) { s += vals[j]; ss += vals[j] * vals[j]; }
#pragma unroll
        for (int off = 32; off > 0; off >>= 1) {
            s += __shfl_xor(s, off);
            ss += __shfl_xor(ss, off);
        }
        const float mean = s * (1.f / 768.f);
        const float var = ss * (1.f / 768.f) - mean * mean;
        const float rstd = rsqrtf(var + 1e-5f);
#pragma unroll
        for (int c = 0; c < 3; ++c) {
            u16x4 o;
#pragma unroll
            for (int q = 0; q < 4; ++q)
                o[q] = f2bf((vals[c*4+q] - mean) * rstd * g[c*4+q] + be[c*4+q]);
            *(u16x4*)&xfn[n * LDK + c * 256 + lane * 4] = o;
        }
    }
    for (int idx = tid; idx < 3 * 768; idx += 256)
        xfn[(77 + idx / 768) * LDK + (idx % 768)] = 0;
    __syncthreads();

    const int nb = jt * 4 + w;
    f32x4 acc[5];
#pragma unroll
    for (int m = 0; m < 5; ++m) { acc[m][0]=0.f; acc[m][1]=0.f; acc[m][2]=0.f; acc[m][3]=0.f; }
    for (int kk = 0; kk < 24; ++kk) {
        const bf16x8 bw = *(const bf16x8*)&kv_wf[((nb * 24 + kk) * 64 + lane) * 8];
#pragma unroll
        for (int m = 0; m < 5; ++m) {
            const bf16x8 a = *(const bf16x8*)&xfn[(m * 16 + l15) * LDK + kk * 32 + lg * 8];
            acc[m] = MFMA16(a, bw, acc[m]);
        }
    }
    const int j = nb * 16 + l15;
    const float bias = (j < 512) ? kb[j] : vb[j - 512];
#pragma unroll
    for (int m = 0; m < 5; ++m) {
#pragma unroll
        for (int reg = 0; reg < 4; ++reg) {
            const int n = m * 16 + lg * 4 + reg;
            if (n < 77)
                kv[(long)(b * 77 + n) * 1024 + j] = acc[m][reg] + bias;
        }
    }
}

// ------------------------------------------------------------------
// att: per (b,h): softmax_n(k) then att = k^T v [64x64]; bf16 B-frag out.
// v2: softmax parallelized over all 256 threads.
// ------------------------------------------------------------------
__global__ __launch_bounds__(256) void att_kernel(
    const float* __restrict__ kv, unsigned short* __restrict__ att_fr)
{
    const int b = blockIdx.x >> 3;
    const int h = blockIdx.x & 7;
    __shared__ float k_lds[77][65];
    __shared__ float v_lds[77][65];
    __shared__ float att_lds[64][65];
    __shared__ float red[4][64];
    const int tid = threadIdx.x;

    for (int idx = tid; idx < 77 * 64; idx += 256) {
        const int n = idx >> 6, d = idx & 63;
        const long base = (long)(b * 77 + n) * 1024 + h * 64 + d;
        k_lds[n][d] = kv[base];
        v_lds[n][d] = kv[base + 512];
    }
    __syncthreads();

    {
        const int col = tid & 63, q = tid >> 6;
        float mx = -1e30f;
        for (int n = q; n < 77; n += 4) mx = fmaxf(mx, k_lds[n][col]);
        red[q][col] = mx;
        __syncthreads();
        mx = fmaxf(fmaxf(red[0][col], red[1][col]), fmaxf(red[2][col], red[3][col]));
        __syncthreads();
        float s = 0.f;
        for (int n = q; n < 77; n += 4) {
            const float e = __expf(k_lds[n][col] - mx);
            k_lds[n][col] = e;
            s += e;
        }
        red[q][col] = s;
        __syncthreads();
        const float inv = 1.f / (red[0][col] + red[1][col] + red[2][col] + red[3][col]);
        for (int n = q; n < 77; n += 4) k_lds[n][col] *= inv;
    }
    __syncthreads();
    {
        const int l = tid & 63, db = (tid >> 6) * 16;
        float a[16];
#pragma unroll
        for (int i = 0; i < 16; ++i) a[i] = 0.f;
        for (int n = 0; n < 77; ++n) {
            const float vv = v_lds[n][l];
#pragma unroll
            for (int i = 0; i < 16; ++i) a[i] += k_lds[n][db + i] * vv;
        }
#pragma unroll
        for (int i = 0; i < 16; ++i) att_lds[db + i][l] = a[i];
    }
    __syncthreads();
    const long hb8 = (long)(b * 8 + h) * 4096;
    for (int idx = tid; idx < 4096; idx += 256) {
        const int i = idx & 7, lane = (idx >> 3) & 63, kk = (idx >> 9) & 1, nf = (idx >> 10);
        const int d = kk * 32 + ((lane >> 4) << 3) + i;
        const int l = nf * 16 + (lane & 15);
        att_fr[hb8 + (long)(nf * 2 + kk) * 512 + lane * 8 + i] = f2bf(att_lds[d][l]);
    }
}

// ------------------------------------------------------------------
// fused4s: fused4 + single-pass bf16 epilogue. Wave w's GEMM2 output lands
// in the SAME LDS stripe as its (dead) P -> wave-local overwrite, no
// barrier; then ONE barrier + one coalesced read-add-store pass.
// (-4 barriers, -1 staging pass vs fused4.)
// ------------------------------------------------------------------
#define LDA 520   // A/P/y row stride (bf16 elems)

#define WLD(n, kk) (*(const bf16x8*)&wfrag[((((w * 4 + (n)) * 16 + (kk)) * 64) + lane) * 8])
#define ALD(m, kk) (*(const bf16x8*)&xn[((m) * 16 + l15) * LDA + (kk) * 32 + lg * 8])

__global__ __launch_bounds__(512, 4) void fused4s(
    const float* __restrict__ x, const unsigned short* __restrict__ wfrag,
    const float* __restrict__ qb, const float* __restrict__ ng,
    const float* __restrict__ nbt, const unsigned short* __restrict__ att_fr,
    float* __restrict__ out)
{
    __shared__ unsigned short xn[64 * LDA];      // 66560 B: A-tile -> P -> y(bf16)
    const int tid = threadIdx.x;
    const int lane = tid & 63;
    const int w = tid >> 6;        // 0..7 == head
    const int l15 = lane & 15;
    const int lg = lane >> 4;
    const int b = blockIdx.y;
    const long rowbase = (long)b * 4096 + (long)blockIdx.x * 64;
    const float* xblk = x + rowbase * 512;

    float g[8], be[8];
    {
        const float4 g0 = *(const float4*)(ng + lane * 8);
        const float4 g1 = *(const float4*)(ng + lane * 8 + 4);
        const float4 b0 = *(const float4*)(nbt + lane * 8);
        const float4 b1 = *(const float4*)(nbt + lane * 8 + 4);
        g[0]=g0.x; g[1]=g0.y; g[2]=g0.z; g[3]=g0.w;
        g[4]=g1.x; g[5]=g1.y; g[6]=g1.z; g[7]=g1.w;
        be[0]=b0.x; be[1]=b0.y; be[2]=b0.z; be[3]=b0.w;
        be[4]=b1.x; be[5]=b1.y; be[6]=b1.z; be[7]=b1.w;
    }

    // ---- LN: wave w -> rows w*8..w*8+7, all loads in flight ----
    {
        float vals[8][8];
#pragma unroll
        for (int r = 0; r < 8; ++r) {
            const float* xr = xblk + (w * 8 + r) * 512 + lane * 8;
            const float4 v0 = *(const float4*)xr;
            const float4 v1 = *(const float4*)(xr + 4);
            vals[r][0]=v0.x; vals[r][1]=v0.y; vals[r][2]=v0.z; vals[r][3]=v0.w;
            vals[r][4]=v1.x; vals[r][5]=v1.y; vals[r][6]=v1.z; vals[r][7]=v1.w;
        }
#pragma unroll
        for (int r = 0; r < 8; ++r) {
            float s = 0.f, ss = 0.f;
#pragma unroll
            for (int j = 0; j < 8; ++j) { s += vals[r][j]; ss += vals[r][j] * vals[r][j]; }
#pragma unroll
            for (int off = 32; off > 0; off >>= 1) {
                s += __shfl_xor(s, off);
                ss += __shfl_xor(ss, off);
            }
            const float mean = s * (1.f / 512.f);
            const float var = ss * (1.f / 512.f) - mean * mean;
            const float rstd = rsqrtf(var + 1e-5f);
            u16x8 o;
#pragma unroll
            for (int j = 0; j < 8; ++j)
                o[j] = f2bf((vals[r][j] - mean) * rstd * g[j] + be[j]);
            *(u16x8*)&xn[(w * 8 + r) * LDA + lane * 8] = o;
        }
    }
    __syncthreads();

    // ---- GEMM1: wave w -> ALL 64 rows x cols [w*64, w*64+64) ----
    const int wcol = w * 64;
    f32x4 acc[4][4];
#pragma unroll
    for (int n = 0; n < 4; ++n) {
        const float qbv = qb[wcol + n * 16 + l15];
#pragma unroll
        for (int m = 0; m < 4; ++m) {
            acc[m][n][0]=qbv; acc[m][n][1]=qbv; acc[m][n][2]=qbv; acc[m][n][3]=qbv;
        }
    }

    {
        bf16x8 aC[4], bC[4];
#pragma unroll
        for (int m = 0; m < 4; ++m) aC[m] = ALD(m, 0);
#pragma unroll
        for (int n = 0; n < 4; ++n) bC[n] = WLD(n, 0);
#pragma unroll
        for (int kk = 0; kk < 16; ++kk) {
            bf16x8 aN[4], bN[4];
            if (kk < 15) {
#pragma unroll
                for (int m = 0; m < 4; ++m) aN[m] = ALD(m, kk + 1);
#pragma unroll
                for (int n = 0; n < 4; ++n) bN[n] = WLD(n, kk + 1);
            }
#pragma unroll
            for (int n = 0; n < 4; ++n)
#pragma unroll
                for (int m = 0; m < 4; ++m)
                    acc[m][n] = MFMA16(aC[m], bC[n], acc[m][n]);
            if (kk < 15) {
#pragma unroll
                for (int m = 0; m < 4; ++m) aC[m] = aN[m];
#pragma unroll
                for (int n = 0; n < 4; ++n) bC[n] = bN[n];
            }
        }
    }

    // ---- softmax over head w's 64 cols (4 frags x 16 lanes) ----
#pragma unroll
    for (int m = 0; m < 4; ++m) {
#pragma unroll
        for (int reg = 0; reg < 4; ++reg) {
            float mx = fmaxf(fmaxf(acc[m][0][reg], acc[m][1][reg]),
                             fmaxf(acc[m][2][reg], acc[m][3][reg]));
#pragma unroll
            for (int off = 1; off < 16; off <<= 1)
                mx = fmaxf(mx, __shfl_xor(mx, off));
            const float e0 = __expf(acc[m][0][reg] - mx);
            const float e1 = __expf(acc[m][1][reg] - mx);
            const float e2 = __expf(acc[m][2][reg] - mx);
            const float e3 = __expf(acc[m][3][reg] - mx);
            float sm = e0 + e1 + e2 + e3;
#pragma unroll
            for (int off = 1; off < 16; off <<= 1)
                sm += __shfl_xor(sm, off);
            const float inv = 1.f / sm;
            acc[m][0][reg] = e0 * inv;
            acc[m][1][reg] = e1 * inv;
            acc[m][2][reg] = e2 * inv;
            acc[m][3][reg] = e3 * inv;
        }
    }

    // ---- hoist att_fr B-fragments (P-independent) ----
    bf16x8 att_b[2][4];
#pragma unroll
    for (int kk = 0; kk < 2; ++kk)
#pragma unroll
        for (int nf = 0; nf < 4; ++nf)
            att_b[kk][nf] = *(const bf16x8*)&att_fr[
                (long)(b * 8 + w) * 4096 + (long)(nf * 2 + kk) * 512 + lane * 8];

    // ---- ONE barrier: all waves' GEMM1 xn reads complete ----
    __syncthreads();

    // P -> own LDS stripe (cols wcol..wcol+64); wave-local, no extra barrier.
#pragma unroll
    for (int m = 0; m < 4; ++m)
#pragma unroll
        for (int n = 0; n < 4; ++n)
#pragma unroll
            for (int reg = 0; reg < 4; ++reg)
                xn[(m * 16 + lg * 4 + reg) * LDA + wcol + n * 16 + l15] =
                    f2bf(acc[m][n][reg]);

    // ---- GEMM2: wave w (head w) reads back ONLY its own stripe ----
    f32x4 acc2[4][4];
#pragma unroll
    for (int m2 = 0; m2 < 4; ++m2)
#pragma unroll
        for (int nf = 0; nf < 4; ++nf) {
            acc2[m2][nf][0]=0.f; acc2[m2][nf][1]=0.f; acc2[m2][nf][2]=0.f; acc2[m2][nf][3]=0.f;
        }
#pragma unroll
    for (int kk = 0; kk < 2; ++kk) {
        bf16x8 a2[4];
#pragma unroll
        for (int m2 = 0; m2 < 4; ++m2)
            a2[m2] = *(const bf16x8*)&xn[(m2 * 16 + l15) * LDA + wcol + kk * 32 + lg * 8];
#pragma unroll
        for (int nf = 0; nf < 4; ++nf) {
#pragma unroll
            for (int m2 = 0; m2 < 4; ++m2)
                acc2[m2][nf] = MFMA16(a2[m2], att_b[kk][nf], acc2[m2][nf]);
        }
    }

    // ---- y (bf16) -> SAME stripe as P: wave-local overwrite, no barrier ----
#pragma unroll
    for (int m2 = 0; m2 < 4; ++m2)
#pragma unroll
        for (int nf = 0; nf < 4; ++nf)
#pragma unroll
            for (int reg = 0; reg < 4; ++reg)
                xn[(m2 * 16 + lg * 4 + reg) * LDA + wcol + nf * 16 + l15] =
                    f2bf(acc2[m2][nf][reg]);
    __syncthreads();   // single barrier: y complete everywhere

    // ---- epilogue: one coalesced read-add-store pass (8 thr/row) ----
    {
        const int row = tid >> 3;              // 0..63
        const int c8 = (tid & 7) * 8;          // 0..56
        const long grow = rowbase + row;
#pragma unroll
        for (int j = 0; j < 8; ++j) {
            const int col = c8 + j * 64;
            const u16x8 yv = *(const u16x8*)&xn[row * LDA + col];
            const long gi = grow * 512 + col;
            const float4 x0 = *(const float4*)&x[gi];
            const float4 x1 = *(const float4*)&x[gi + 4];
            float4 o0, o1;
            o0.x = x0.x + bf2f(yv[0]); o0.y = x0.y + bf2f(yv[1]);
            o0.z = x0.z + bf2f(yv[2]); o0.w = x0.w + bf2f(yv[3]);
            o1.x = x1.x + bf2f(yv[4]); o1.y = x1.y + bf2f(yv[5]);
            o1.z = x1.z + bf2f(yv[6]); o1.w = x1.w + bf2f(yv[7]);
            *(float4*)&out[gi] = o0;
            *(float4*)&out[gi + 4] = o1;
        }
    }
}

// ------------------------------------------------------------------
extern "C" void kernel_launch(void* const* d_in, const int* in_sizes, int n_in,
                              void* d_out, int out_size, void* d_ws, size_t ws_size,
                              hipStream_t stream) {
    const float* x  = (const float*)d_in[0];
    const float* xf = (const float*)d_in[1];
    const float* qw = (const float*)d_in[2];
    const float* qb = (const float*)d_in[3];
    const float* kw = (const float*)d_in[4];
    const float* kb = (const float*)d_in[5];
    const float* vw = (const float*)d_in[6];
    const float* vb = (const float*)d_in[7];
    const float* ng = (const float*)d_in[8];
    const float* nb = (const float*)d_in[9];
    const float* tg = (const float*)d_in[10];
    const float* tb = (const float*)d_in[11];
    float* out = (float*)d_out;

    char* ws = (char*)d_ws;
    unsigned short* wfrag  = (unsigned short*)(ws);                 // 512 KB
    unsigned short* kv_wf  = (unsigned short*)(ws + 524288);        // 1.5 MB
    float*          kv     = (float*)(ws + 2097152);                // ~4.8 MB
    unsigned short* att_fr = (unsigned short*)(ws + 7143424);       // 1 MB

    prep_kernel<<<dim3(4096), dim3(256), 0, stream>>>(qw, kw, vw, wfrag, kv_wf);
    kv_kernel<<<dim3(16, 16), dim3(256), 0, stream>>>(xf, kv_wf, kb, vb, tg, tb, kv);
    att_kernel<<<dim3(128), dim3(256), 0, stream>>>(kv, att_fr);
    fused4s<<<dim3(64, 16), dim3(512), 0, stream>>>(x, wfrag, qb, ng, nb, att_fr, out);
}

// Round 15
// 140.045 us; speedup vs baseline: 1.0497x; 1.0497x over previous
//
#include <hip/hip_runtime.h>

typedef __attribute__((ext_vector_type(8))) __bf16 bf16x8;
typedef __attribute__((ext_vector_type(4))) float f32x4;
typedef __attribute__((ext_vector_type(8))) unsigned short u16x8;
typedef __attribute__((ext_vector_type(4))) unsigned short u16x4;

#define MFMA16(a, b, c) __builtin_amdgcn_mfma_f32_16x16x32_bf16((a), (b), (c), 0, 0, 0)

static __device__ __forceinline__ unsigned short f2bf(float f) {
    union { float f; unsigned int u; } v;
    v.f = f;
    unsigned int r = v.u + 0x7FFFu + ((v.u >> 16) & 1u);
    return (unsigned short)(r >> 16);
}

// ------------------------------------------------------------------
// prep: weights -> bf16 MFMA B-fragment order (wfrag for Q, kv_wf for K/V).
// ------------------------------------------------------------------
__global__ __launch_bounds__(256) void prep_kernel(
    const float* __restrict__ qw, const float* __restrict__ kw,
    const float* __restrict__ vw,
    unsigned short* __restrict__ wfrag, unsigned short* __restrict__ kv_wf)
{
    const int idx = blockIdx.x * 256 + threadIdx.x;
    if (idx < 262144) {
        const int i = idx & 7, lane = (idx >> 3) & 63, kk = (idx >> 9) & 15, nb = idx >> 13;
        const int row = nb * 16 + (lane & 15);
        const int col = kk * 32 + ((lane >> 4) << 3) + i;
        wfrag[idx] = f2bf(qw[row * 512 + col]);
    } else {
        const int jdx = idx - 262144;
        const int i = jdx & 7, lane = (jdx >> 3) & 63;
        const int rest = jdx >> 9;
        const int kk = rest % 24, nb = rest / 24;
        const int j = nb * 16 + (lane & 15);
        const int k = kk * 32 + ((lane >> 4) << 3) + i;
        kv_wf[jdx] = f2bf(j < 512 ? kw[j * 768 + k] : vw[(j - 512) * 768 + k]);
    }
}

// ------------------------------------------------------------------
// kv: fused LN(xf) + K/V projection. grid (jt=16, b=16). block = 256.
// ------------------------------------------------------------------
#define LDK 776
__global__ __launch_bounds__(256) void kv_kernel(
    const float* __restrict__ xf, const unsigned short* __restrict__ kv_wf,
    const float* __restrict__ kb, const float* __restrict__ vb,
    const float* __restrict__ tg, const float* __restrict__ tb,
    float* __restrict__ kv)
{
    __shared__ unsigned short xfn[80 * LDK];
    const int tid = threadIdx.x;
    const int lane = tid & 63;
    const int w = tid >> 6;
    const int l15 = lane & 15;
    const int lg = lane >> 4;
    const int b = blockIdx.y;
    const int jt = blockIdx.x;

    float g[12], be[12];
#pragma unroll
    for (int c = 0; c < 3; ++c) {
        const float4 gv = *(const float4*)(tg + c * 256 + lane * 4);
        const float4 bv = *(const float4*)(tb + c * 256 + lane * 4);
        g[c*4+0]=gv.x; g[c*4+1]=gv.y; g[c*4+2]=gv.z; g[c*4+3]=gv.w;
        be[c*4+0]=bv.x; be[c*4+1]=bv.y; be[c*4+2]=bv.z; be[c*4+3]=bv.w;
    }

    for (int n = w; n < 77; n += 4) {
        const float* xr = xf + (long)(b * 77 + n) * 768;
        float vals[12];
#pragma unroll
        for (int c = 0; c < 3; ++c) {
            const float4 v4 = *(const float4*)(xr + c * 256 + lane * 4);
            vals[c*4+0]=v4.x; vals[c*4+1]=v4.y; vals[c*4+2]=v4.z; vals[c*4+3]=v4.w;
        }
        float s = 0.f, ss = 0.f;
#pragma unroll
        for (int j = 0; j < 12; ++j) { s += vals[j]; ss += vals[j] * vals[j]; }
#pragma unroll
        for (int off = 32; off > 0; off >>= 1) {
            s += __shfl_xor(s, off);
            ss += __shfl_xor(ss, off);
        }
        const float mean = s * (1.f / 768.f);
        const float var = ss * (1.f / 768.f) - mean * mean;
        const float rstd = rsqrtf(var + 1e-5f);
#pragma unroll
        for (int c = 0; c < 3; ++c) {
            u16x4 o;
#pragma unroll
            for (int q = 0; q < 4; ++q)
                o[q] = f2bf((vals[c*4+q] - mean) * rstd * g[c*4+q] + be[c*4+q]);
            *(u16x4*)&xfn[n * LDK + c * 256 + lane * 4] = o;
        }
    }
    for (int idx = tid; idx < 3 * 768; idx += 256)
        xfn[(77 + idx / 768) * LDK + (idx % 768)] = 0;
    __syncthreads();

    const int nb = jt * 4 + w;
    f32x4 acc[5];
#pragma unroll
    for (int m = 0; m < 5; ++m) { acc[m][0]=0.f; acc[m][1]=0.f; acc[m][2]=0.f; acc[m][3]=0.f; }
    for (int kk = 0; kk < 24; ++kk) {
        const bf16x8 bw = *(const bf16x8*)&kv_wf[((nb * 24 + kk) * 64 + lane) * 8];
#pragma unroll
        for (int m = 0; m < 5; ++m) {
            const bf16x8 a = *(const bf16x8*)&xfn[(m * 16 + l15) * LDK + kk * 32 + lg * 8];
            acc[m] = MFMA16(a, bw, acc[m]);
        }
    }
    const int j = nb * 16 + l15;
    const float bias = (j < 512) ? kb[j] : vb[j - 512];
#pragma unroll
    for (int m = 0; m < 5; ++m) {
#pragma unroll
        for (int reg = 0; reg < 4; ++reg) {
            const int n = m * 16 + lg * 4 + reg;
            if (n < 77)
                kv[(long)(b * 77 + n) * 1024 + j] = acc[m][reg] + bias;
        }
    }
}

// ------------------------------------------------------------------
// att: per (b,h): softmax_n(k) then att = k^T v [64x64]; bf16 B-frag out.
// v2: softmax parallelized over all 256 threads (4-way row split + LDS
// reduce).
// ------------------------------------------------------------------
__global__ __launch_bounds__(256) void att_kernel(
    const float* __restrict__ kv, unsigned short* __restrict__ att_fr)
{
    const int b = blockIdx.x >> 3;
    const int h = blockIdx.x & 7;
    __shared__ float k_lds[77][65];
    __shared__ float v_lds[77][65];
    __shared__ float att_lds[64][65];
    __shared__ float red[4][64];
    const int tid = threadIdx.x;

    for (int idx = tid; idx < 77 * 64; idx += 256) {
        const int n = idx >> 6, d = idx & 63;
        const long base = (long)(b * 77 + n) * 1024 + h * 64 + d;
        k_lds[n][d] = kv[base];
        v_lds[n][d] = kv[base + 512];
    }
    __syncthreads();

    {
        const int col = tid & 63, q = tid >> 6;
        float mx = -1e30f;
        for (int n = q; n < 77; n += 4) mx = fmaxf(mx, k_lds[n][col]);
        red[q][col] = mx;
        __syncthreads();
        mx = fmaxf(fmaxf(red[0][col], red[1][col]), fmaxf(red[2][col], red[3][col]));
        __syncthreads();
        float s = 0.f;
        for (int n = q; n < 77; n += 4) {
            const float e = __expf(k_lds[n][col] - mx);
            k_lds[n][col] = e;
            s += e;
        }
        red[q][col] = s;
        __syncthreads();
        const float inv = 1.f / (red[0][col] + red[1][col] + red[2][col] + red[3][col]);
        for (int n = q; n < 77; n += 4) k_lds[n][col] *= inv;
    }
    __syncthreads();
    {
        const int l = tid & 63, db = (tid >> 6) * 16;
        float a[16];
#pragma unroll
        for (int i = 0; i < 16; ++i) a[i] = 0.f;
        for (int n = 0; n < 77; ++n) {
            const float vv = v_lds[n][l];
#pragma unroll
            for (int i = 0; i < 16; ++i) a[i] += k_lds[n][db + i] * vv;
        }
#pragma unroll
        for (int i = 0; i < 16; ++i) att_lds[db + i][l] = a[i];
    }
    __syncthreads();
    const long hb8 = (long)(b * 8 + h) * 4096;
    for (int idx = tid; idx < 4096; idx += 256) {
        const int i = idx & 7, lane = (idx >> 3) & 63, kk = (idx >> 9) & 1, nf = (idx >> 10);
        const int d = kk * 32 + ((lane >> 4) << 3) + i;
        const int l = nf * 16 + (lane & 15);
        att_fr[hb8 + (long)(nf * 2 + kk) * 512 + lane * 8 + i] = f2bf(att_lds[d][l]);
    }
}

// ------------------------------------------------------------------
// fused4: session-best (bench 140.05 us). wave = head for both GEMMs;
// zero wfrag duplication; single-barrier P hand-off; LDS-staged coalesced
// residual epilogue. LDS 66.5 KB, 2 blk/CU.
// ------------------------------------------------------------------
#define LDA 520   // A/P row stride (bf16 elems)
#define LDY 516   // y row stride (f32 elems)

#define WLD(n, kk) (*(const bf16x8*)&wfrag[((((w * 4 + (n)) * 16 + (kk)) * 64) + lane) * 8])
#define ALD(m, kk) (*(const bf16x8*)&xn[((m) * 16 + l15) * LDA + (kk) * 32 + lg * 8])

__global__ __launch_bounds__(512, 4) void fused4(
    const float* __restrict__ x, const unsigned short* __restrict__ wfrag,
    const float* __restrict__ qb, const float* __restrict__ ng,
    const float* __restrict__ nbt, const unsigned short* __restrict__ att_fr,
    float* __restrict__ out)
{
    __shared__ char smem[64 * LDA * 2];          // 66560 B
    unsigned short* const xn = (unsigned short*)smem;
    float* const ylds = (float*)smem;
    const int tid = threadIdx.x;
    const int lane = tid & 63;
    const int w = tid >> 6;        // 0..7 == head
    const int l15 = lane & 15;
    const int lg = lane >> 4;
    const int b = blockIdx.y;
    const long rowbase = (long)b * 4096 + (long)blockIdx.x * 64;
    const float* xblk = x + rowbase * 512;

    float g[8], be[8];
    {
        const float4 g0 = *(const float4*)(ng + lane * 8);
        const float4 g1 = *(const float4*)(ng + lane * 8 + 4);
        const float4 b0 = *(const float4*)(nbt + lane * 8);
        const float4 b1 = *(const float4*)(nbt + lane * 8 + 4);
        g[0]=g0.x; g[1]=g0.y; g[2]=g0.z; g[3]=g0.w;
        g[4]=g1.x; g[5]=g1.y; g[6]=g1.z; g[7]=g1.w;
        be[0]=b0.x; be[1]=b0.y; be[2]=b0.z; be[3]=b0.w;
        be[4]=b1.x; be[5]=b1.y; be[6]=b1.z; be[7]=b1.w;
    }

    // ---- LN: wave w -> rows w*8..w*8+7, all loads in flight ----
    {
        float vals[8][8];
#pragma unroll
        for (int r = 0; r < 8; ++r) {
            const float* xr = xblk + (w * 8 + r) * 512 + lane * 8;
            const float4 v0 = *(const float4*)xr;
            const float4 v1 = *(const float4*)(xr + 4);
            vals[r][0]=v0.x; vals[r][1]=v0.y; vals[r][2]=v0.z; vals[r][3]=v0.w;
            vals[r][4]=v1.x; vals[r][5]=v1.y; vals[r][6]=v1.z; vals[r][7]=v1.w;
        }
#pragma unroll
        for (int r = 0; r < 8; ++r) {
            float s = 0.f, ss = 0.f;
#pragma unroll
            for (int j = 0; j < 8; ++j) { s += vals[r][j]; ss += vals[r][j] * vals[r][j]; }
#pragma unroll
            for (int off = 32; off > 0; off >>= 1) {
                s += __shfl_xor(s, off);
                ss += __shfl_xor(ss, off);
            }
            const float mean = s * (1.f / 512.f);
            const float var = ss * (1.f / 512.f) - mean * mean;
            const float rstd = rsqrtf(var + 1e-5f);
            u16x8 o;
#pragma unroll
            for (int j = 0; j < 8; ++j)
                o[j] = f2bf((vals[r][j] - mean) * rstd * g[j] + be[j]);
            *(u16x8*)&xn[(w * 8 + r) * LDA + lane * 8] = o;
        }
    }
    __syncthreads();

    // ---- GEMM1: wave w -> ALL 64 rows x cols [w*64, w*64+64) ----
    const int wcol = w * 64;
    f32x4 acc[4][4];
#pragma unroll
    for (int n = 0; n < 4; ++n) {
        const float qbv = qb[wcol + n * 16 + l15];
#pragma unroll
        for (int m = 0; m < 4; ++m) {
            acc[m][n][0]=qbv; acc[m][n][1]=qbv; acc[m][n][2]=qbv; acc[m][n][3]=qbv;
        }
    }

    {
        bf16x8 aC[4], bC[4];
#pragma unroll
        for (int m = 0; m < 4; ++m) aC[m] = ALD(m, 0);
#pragma unroll
        for (int n = 0; n < 4; ++n) bC[n] = WLD(n, 0);
#pragma unroll
        for (int kk = 0; kk < 16; ++kk) {
            bf16x8 aN[4], bN[4];
            if (kk < 15) {
#pragma unroll
                for (int m = 0; m < 4; ++m) aN[m] = ALD(m, kk + 1);
#pragma unroll
                for (int n = 0; n < 4; ++n) bN[n] = WLD(n, kk + 1);
            }
#pragma unroll
            for (int n = 0; n < 4; ++n)
#pragma unroll
                for (int m = 0; m < 4; ++m)
                    acc[m][n] = MFMA16(aC[m], bC[n], acc[m][n]);
            if (kk < 15) {
#pragma unroll
                for (int m = 0; m < 4; ++m) aC[m] = aN[m];
#pragma unroll
                for (int n = 0; n < 4; ++n) bC[n] = bN[n];
            }
        }
    }

    // ---- softmax over head w's 64 cols (4 frags x 16 lanes) ----
#pragma unroll
    for (int m = 0; m < 4; ++m) {
#pragma unroll
        for (int reg = 0; reg < 4; ++reg) {
            float mx = fmaxf(fmaxf(acc[m][0][reg], acc[m][1][reg]),
                             fmaxf(acc[m][2][reg], acc[m][3][reg]));
#pragma unroll
            for (int off = 1; off < 16; off <<= 1)
                mx = fmaxf(mx, __shfl_xor(mx, off));
            const float e0 = __expf(acc[m][0][reg] - mx);
            const float e1 = __expf(acc[m][1][reg] - mx);
            const float e2 = __expf(acc[m][2][reg] - mx);
            const float e3 = __expf(acc[m][3][reg] - mx);
            float sm = e0 + e1 + e2 + e3;
#pragma unroll
            for (int off = 1; off < 16; off <<= 1)
                sm += __shfl_xor(sm, off);
            const float inv = 1.f / sm;
            acc[m][0][reg] = e0 * inv;
            acc[m][1][reg] = e1 * inv;
            acc[m][2][reg] = e2 * inv;
            acc[m][3][reg] = e3 * inv;
        }
    }

    // ---- hoist att_fr B-fragments (P-independent) ----
    bf16x8 att_b[2][4];
#pragma unroll
    for (int kk = 0; kk < 2; ++kk)
#pragma unroll
        for (int nf = 0; nf < 4; ++nf)
            att_b[kk][nf] = *(const bf16x8*)&att_fr[
                (long)(b * 8 + w) * 4096 + (long)(nf * 2 + kk) * 512 + lane * 8];

    // ---- ONE barrier: all waves' GEMM1 xn reads complete ----
    __syncthreads();

    // P -> own LDS stripe (cols wcol..wcol+64); wave-local, no extra barrier.
#pragma unroll
    for (int m = 0; m < 4; ++m)
#pragma unroll
        for (int n = 0; n < 4; ++n)
#pragma unroll
            for (int reg = 0; reg < 4; ++reg)
                xn[(m * 16 + lg * 4 + reg) * LDA + wcol + n * 16 + l15] =
                    f2bf(acc[m][n][reg]);

    // ---- GEMM2: wave w (head w) reads back ONLY its own stripe ----
    f32x4 acc2[4][4];
#pragma unroll
    for (int m2 = 0; m2 < 4; ++m2)
#pragma unroll
        for (int nf = 0; nf < 4; ++nf) {
            acc2[m2][nf][0]=0.f; acc2[m2][nf][1]=0.f; acc2[m2][nf][2]=0.f; acc2[m2][nf][3]=0.f;
        }
#pragma unroll
    for (int kk = 0; kk < 2; ++kk) {
        bf16x8 a2[4];
#pragma unroll
        for (int m2 = 0; m2 < 4; ++m2)
            a2[m2] = *(const bf16x8*)&xn[(m2 * 16 + l15) * LDA + wcol + kk * 32 + lg * 8];
#pragma unroll
        for (int nf = 0; nf < 4; ++nf) {
#pragma unroll
            for (int m2 = 0; m2 < 4; ++m2)
                acc2[m2][nf] = MFMA16(a2[m2], att_b[kk][nf], acc2[m2][nf]);
        }
    }
    __syncthreads();   // all P reads done; ylds may overwrite

    // ---- epilogue: two 32-row halves staged through LDS, coalesced I/O ----
#pragma unroll
    for (int hh = 0; hh < 2; ++hh) {
#pragma unroll
        for (int m2h = 0; m2h < 2; ++m2h) {
            const int m2 = hh * 2 + m2h;
#pragma unroll
            for (int nf = 0; nf < 4; ++nf)
#pragma unroll
                for (int reg = 0; reg < 4; ++reg)
                    ylds[(m2h * 16 + lg * 4 + reg) * LDY + w * 64 + nf * 16 + l15] =
                        acc2[m2][nf][reg];
        }
        __syncthreads();
        const int row = tid >> 4;
        const long grow = rowbase + hh * 32 + row;
#pragma unroll
        for (int j = 0; j < 8; ++j) {
            const int col = j * 64 + (tid & 15) * 4;
            const float4 yv = *(const float4*)&ylds[row * LDY + col];
            const long gi = grow * 512 + col;
            const float4 xv = *(const float4*)&x[gi];
            float4 ov;
            ov.x = xv.x + yv.x; ov.y = xv.y + yv.y;
            ov.z = xv.z + yv.z; ov.w = xv.w + yv.w;
            *(float4*)&out[gi] = ov;
        }
        __syncthreads();
    }
}

// ------------------------------------------------------------------
extern "C" void kernel_launch(void* const* d_in, const int* in_sizes, int n_in,
                              void* d_out, int out_size, void* d_ws, size_t ws_size,
                              hipStream_t stream) {
    const float* x  = (const float*)d_in[0];
    const float* xf = (const float*)d_in[1];
    const float* qw = (const float*)d_in[2];
    const float* qb = (const float*)d_in[3];
    const float* kw = (const float*)d_in[4];
    const float* kb = (const float*)d_in[5];
    const float* vw = (const float*)d_in[6];
    const float* vb = (const float*)d_in[7];
    const float* ng = (const float*)d_in[8];
    const float* nb = (const float*)d_in[9];
    const float* tg = (const float*)d_in[10];
    const float* tb = (const float*)d_in[11];
    float* out = (float*)d_out;

    char* ws = (char*)d_ws;
    unsigned short* wfrag  = (unsigned short*)(ws);                 // 512 KB
    unsigned short* kv_wf  = (unsigned short*)(ws + 524288);        // 1.5 MB
    float*          kv     = (float*)(ws + 2097152);                // ~4.8 MB
    unsigned short* att_fr = (unsigned short*)(ws + 7143424);       // 1 MB

    prep_kernel<<<dim3(4096), dim3(256), 0, stream>>>(qw, kw, vw, wfrag, kv_wf);
    kv_kernel<<<dim3(16, 16), dim3(256), 0, stream>>>(xf, kv_wf, kb, vb, tg, tb, kv);
    att_kernel<<<dim3(128), dim3(256), 0, stream>>>(kv, att_fr);
    fused4<<<dim3(64, 16), dim3(512), 0, stream>>>(x, wfrag, qb, ng, nb, att_fr, out);
}